// Round 3
// baseline (54.938 us; speedup 1.0000x reference)
//
#include <hip/hip_runtime.h>

#define D    256
#define KCB  2048
#define HW   1024
#define BN   64

typedef __attribute__((ext_vector_type(8))) short bf16x8;
typedef __attribute__((ext_vector_type(4))) float f32x4;

__device__ __forceinline__ unsigned short f2bf(float f) {
  union { float f; unsigned u; } v; v.f = f;
  unsigned r = v.u + 0x7fffu + ((v.u >> 16) & 1u);   // RTNE
  return (unsigned short)(r >> 16);
}

// K1: codebook fp32 -> bf16 (row-major 2048x256) + cnorm[row] = ||c||^2
__global__ __launch_bounds__(256) void vq_prep(const float* __restrict__ cb,
                                               unsigned short* __restrict__ cbh,
                                               float* __restrict__ cnorm) {
  int row = blockIdx.x;
  int t = threadIdx.x;
  float c = cb[(size_t)row * D + t];
  cbh[(size_t)row * D + t] = f2bf(c);
  float s = c * c;
#pragma unroll
  for (int off = 32; off; off >>= 1) s += __shfl_down(s, off, 64);
  __shared__ float ws4[4];
  if ((t & 63) == 0) ws4[t >> 6] = s;
  __syncthreads();
  if (t == 0) cnorm[row] = (ws4[0] + ws4[1]) + (ws4[2] + ws4[3]);
}

// K2: half-codebook distance GEMM, BARRIER-FREE main loop.
// grid = 256 coltiles x 2 halves = 512 (2 blocks/CU).
// B (z-tile) entirely in registers; A fragments loaded straight from
// global (codebook is L2-resident) -- no LDS staging, no s_barrier,
// no vmcnt choreography in the K-loop.
__global__ __launch_bounds__(256, 2) void vq_main(
    const float* __restrict__ z, const unsigned short* __restrict__ cbh,
    const float* __restrict__ cnorm,
    float* __restrict__ bestv_ws, int* __restrict__ bestk_ws,
    float* __restrict__ zsq_ws) {
  __shared__ __align__(16) char smem[37888];
  char* ZT = smem;                                      // [64 cols][256 k] bf16, swizzled
  float* cnorm_s = (float*)(smem + 32768);              // 1024 f32
  float* zred = (float*)(smem + 36864);                 // 256 f32

  const int t = threadIdx.x;
  const int l = t & 63, w = t >> 6, g = l >> 4, cl = l & 15;
  const int bid = blockIdx.x;
  const int ct = bid >> 1, hf = bid & 1;
  const int b = ct >> 4, m0 = (ct & 15) * BN;
  const int rowbase = hf * 1024;
  const float* zb = z + (size_t)b * (D * HW) + m0;

  // ---- prologue: stage ZT = bf16(-2z) transposed+swizzled; zsq partials ----
  float zp = 0.f;
#pragma unroll 4
  for (int it = 0; it < 32; ++it) {
    int d0 = it * 8 + w * 2;
    float v0 = zb[(size_t)d0 * HW + l];
    float v1 = zb[(size_t)(d0 + 1) * HW + l];
    zp += v0 * v0 + v1 * v1;
    unsigned pk = (unsigned)f2bf(-2.f * v0) | ((unsigned)f2bf(-2.f * v1) << 16);
    *(unsigned*)(ZT + l * 512 + ((d0 * 2) ^ ((l & 7) << 4))) = pk;
  }
  zred[t] = zp;
#pragma unroll
  for (int i = 0; i < 4; ++i) cnorm_s[t + i * 256] = cnorm[rowbase + t + i * 256];
  __syncthreads();
  if (t < 64)
    zsq_ws[ct * 64 + t] = (zred[t] + zred[t + 64]) + (zred[t + 128] + zred[t + 192]);

  // ---- load ALL B fragments to registers ----
  bf16x8 bvc[4][8];
#pragma unroll
  for (int s = 0; s < 8; ++s)
#pragma unroll
    for (int cf = 0; cf < 4; ++cf) {
      int c = cf * 16 + cl;
      bvc[cf][s] = *(const bf16x8*)(ZT + c * 512 + ((s * 64 + g * 16) ^ ((c & 7) << 4)));
    }

  float bestvr[4]; int bestkr[4];
#pragma unroll
  for (int cf = 0; cf < 4; ++cf) { bestvr[cf] = 3.4e38f; bestkr[cf] = 0; }

  // ---- barrier-free M-loop: A fragments direct from global (L2) ----
  // A-frag (16x16x32 bf16): lane reads row = base+(l&15), k = (l>>4)*8 .. +8
  for (int mt = 0; mt < 8; ++mt) {
    const unsigned short* abase0 =
        cbh + (((size_t)(rowbase + mt * 128 + w * 32 + cl)) << 8) + (g << 3);
    const unsigned short* abase1 = abase0 + (16 << 8);   // mf=1 is +16 rows

    bf16x8 af0[8], af1[8];
#pragma unroll
    for (int ks = 0; ks < 8; ++ks) {
      af0[ks] = *(const bf16x8*)(abase0 + ks * 32);      // offset:64*ks folds
      af1[ks] = *(const bf16x8*)(abase1 + ks * 32);
    }

    f32x4 acc[2][4];
#pragma unroll
    for (int mf = 0; mf < 2; ++mf)
#pragma unroll
      for (int cf = 0; cf < 4; ++cf) acc[mf][cf] = (f32x4){0.f, 0.f, 0.f, 0.f};

#pragma unroll
    for (int ks = 0; ks < 8; ++ks) {
#pragma unroll
      for (int cf = 0; cf < 4; ++cf) {
        acc[0][cf] = __builtin_amdgcn_mfma_f32_16x16x32_bf16(
            af0[ks], bvc[cf][ks], acc[0][cf], 0, 0, 0);
        acc[1][cf] = __builtin_amdgcn_mfma_f32_16x16x32_bf16(
            af1[ks], bvc[cf][ks], acc[1][cf], 0, 0, 0);
      }
    }

    // ---- argmin update: dist = ||c||^2 + (-2 z . c) ----
#pragma unroll
    for (int mf = 0; mf < 2; ++mf)
#pragma unroll
      for (int i = 0; i < 4; ++i) {
        int lr = mt * 128 + w * 32 + mf * 16 + g * 4 + i;   // C/D row map (m89)
        float cn = cnorm_s[lr];
        int grow = rowbase + lr;
#pragma unroll
        for (int cf = 0; cf < 4; ++cf) {
          float v = cn + acc[mf][cf][i];
          if (v < bestvr[cf]) { bestvr[cf] = v; bestkr[cf] = grow; }
        }
      }
  }

  // ---- reduce argmin across lanes/waves; write per-half results ----
  __syncthreads();   // waves drift in barrier-free loop; realign before LDS reuse
  float* redv = (float*)smem;            // [4 waves][4 cf][16]
  int* redk = (int*)(smem + 1024);
#pragma unroll
  for (int cf = 0; cf < 4; ++cf) {
    float v = bestvr[cf]; int kk = bestkr[cf];
#pragma unroll
    for (int off = 16; off < 64; off <<= 1) {
      float ov = __shfl_xor(v, off, 64);
      int ok = __shfl_xor(kk, off, 64);
      if (ov < v || (ov == v && ok < kk)) { v = ov; kk = ok; }
    }
    if (g == 0) { redv[(w * 4 + cf) * 16 + cl] = v; redk[(w * 4 + cf) * 16 + cl] = kk; }
  }
  __syncthreads();
  if (t < 64) {
    int cf = t >> 4, c2 = t & 15;
    float v = redv[cf * 16 + c2]; int kk = redk[cf * 16 + c2];
#pragma unroll
    for (int w2 = 1; w2 < 4; ++w2) {
      float ov = redv[(w2 * 4 + cf) * 16 + c2];
      int ok = redk[(w2 * 4 + cf) * 16 + c2];
      if (ov < v || (ov == v && ok < kk)) { v = ov; kk = ok; }
    }
    bestv_ws[bid * 64 + t] = v;
    bestk_ws[bid * 64 + t] = kk;
  }
}

// K3: merge halves, gather q (exact fp32 codebook), commitment partial per coltile
__global__ __launch_bounds__(256) void vq_epilogue(
    const float* __restrict__ cb, const float* __restrict__ bestv_ws,
    const int* __restrict__ bestk_ws, const float* __restrict__ zsq_ws,
    float* __restrict__ qout, float* __restrict__ partial) {
  __shared__ int kbest_s[64];
  const int t = threadIdx.x, l = t & 63, w = t >> 6;
  const int ct = blockIdx.x;
  const int b = ct >> 4, m0 = (ct & 15) * BN;
  if (t < 64) {
    float v0 = bestv_ws[(ct * 2 + 0) * 64 + t]; int k0 = bestk_ws[(ct * 2 + 0) * 64 + t];
    float v1 = bestv_ws[(ct * 2 + 1) * 64 + t]; int k1 = bestk_ws[(ct * 2 + 1) * 64 + t];
    int kk = (v1 < v0) ? k1 : k0;
    float vv = (v1 < v0) ? v1 : v0;
    kbest_s[t] = kk;
    float cpart = zsq_ws[ct * 64 + t] + vv;    // sum_d (z-c)^2 for this column
#pragma unroll
    for (int off = 32; off; off >>= 1) cpart += __shfl_down(cpart, off, 64);
    if (t == 0) partial[ct] = cpart;
  }
  __syncthreads();
  int krow = kbest_s[l];
  const float* crow = cb + (size_t)krow * D + w * 64;
  float* qcol = qout + (size_t)b * (D * HW) + m0 + (size_t)(w * 64) * HW + l;
#pragma unroll 4
  for (int i4 = 0; i4 < 16; ++i4) {
    float4 cv = *(const float4*)(crow + i4 * 4);
    qcol[(size_t)(i4 * 4 + 0) * HW] = cv.x;
    qcol[(size_t)(i4 * 4 + 1) * HW] = cv.y;
    qcol[(size_t)(i4 * 4 + 2) * HW] = cv.z;
    qcol[(size_t)(i4 * 4 + 3) * HW] = cv.w;
  }
}

// K4: deterministic reduction of 256 coltile partials -> loss scalars
__global__ __launch_bounds__(256) void vq_finalize(const float* __restrict__ partial,
                                                   float* __restrict__ out) {
  int t = threadIdx.x;
  float s = partial[t];
#pragma unroll
  for (int off = 32; off; off >>= 1) s += __shfl_down(s, off, 64);
  __shared__ float ws4[4];
  if ((t & 63) == 0) ws4[t >> 6] = s;
  __syncthreads();
  if (t == 0) {
    float tot = (ws4[0] + ws4[1]) + (ws4[2] + ws4[3]);
    float commit = tot / 4194304.0f;
    out[4194304] = 0.25f * commit;
    out[4194305] = commit;
  }
}

extern "C" void kernel_launch(void* const* d_in, const int* in_sizes, int n_in,
                              void* d_out, int out_size, void* d_ws, size_t ws_size,
                              hipStream_t stream) {
  const float* z = (const float*)d_in[0];
  const float* cb = (const float*)d_in[1];
  float* out = (float*)d_out;
  char* ws = (char*)d_ws;
  unsigned short* cbh = (unsigned short*)ws;                       // 1 MB
  float* cnorm   = (float*)(ws + 1048576);                         // 8 KB
  float* partial = (float*)(ws + 1056768);                         // 1 KB
  float* bestv_ws = (float*)(ws + 1057792);                        // 128 KB
  int*   bestk_ws = (int*)(ws + 1188864);                          // 128 KB
  float* zsq_ws   = (float*)(ws + 1319936);                        // 64 KB

  vq_prep<<<KCB, 256, 0, stream>>>(cb, cbh, cnorm);
  vq_main<<<512, 256, 0, stream>>>(z, cbh, cnorm, bestv_ws, bestk_ws, zsq_ws);
  vq_epilogue<<<256, 256, 0, stream>>>(cb, bestv_ws, bestk_ws, zsq_ws, out, partial);
  vq_finalize<<<1, 256, 0, stream>>>(partial, out);
}

// Round 4
// 43.667 us; speedup vs baseline: 1.2581x; 1.2581x over previous
//
#include <hip/hip_runtime.h>

#define D    256
#define KCB  2048
#define HW   1024
#define BN   64

typedef __attribute__((ext_vector_type(8))) short bf16x8;
typedef __attribute__((ext_vector_type(4))) float f32x4;

__device__ __forceinline__ unsigned short f2bf(float f) {
  union { float f; unsigned u; } v; v.f = f;
  unsigned r = v.u + 0x7fffu + ((v.u >> 16) & 1u);   // RTNE
  return (unsigned short)(r >> 16);
}

// K1: codebook fp32 -> bf16 (row-major 2048x256) + cnorm[row] = ||c||^2
__global__ __launch_bounds__(256) void vq_prep(const float* __restrict__ cb,
                                               unsigned short* __restrict__ cbh,
                                               float* __restrict__ cnorm) {
  int row = blockIdx.x;
  int t = threadIdx.x;
  float c = cb[(size_t)row * D + t];
  cbh[(size_t)row * D + t] = f2bf(c);
  float s = c * c;
#pragma unroll
  for (int off = 32; off; off >>= 1) s += __shfl_down(s, off, 64);
  __shared__ float ws4[4];
  if ((t & 63) == 0) ws4[t >> 6] = s;
  __syncthreads();
  if (t == 0) cnorm[row] = (ws4[0] + ws4[1]) + (ws4[2] + ws4[3]);
}

__device__ __forceinline__ void stage_chunk(const unsigned short* __restrict__ cbh,
                                            int rowbase, int mt, int kt,
                                            char* dst, int w, int l) {
  // chunk = 128 rows x 64 k, linear LDS dest, k-slot pre-swizzled on global src
#pragma unroll
  for (int i = 0; i < 4; ++i) {
    int r = w * 32 + i * 8 + (l >> 3);
    int kg = (l & 7) ^ (r & 7);
    const unsigned short* gp =
        cbh + (((size_t)(rowbase + mt * 128 + r)) << 8) + kt * 64 + kg * 8;
    __builtin_amdgcn_global_load_lds(
        (const __attribute__((address_space(1))) void*)gp,
        (__attribute__((address_space(3))) void*)(dst + w * 4096 + i * 1024 + l * 16),
        16, 0, 0);
  }
}

// K2: half-codebook distance GEMM. grid = 512 (2 blocks/CU).
// Quad-buffered A staging, ONE barrier per phase, counted vmcnt(8)
// (prefetch depth 2). B (z-tile) entirely in registers.
__global__ __launch_bounds__(256, 2) void vq_main(
    const float* __restrict__ z, const unsigned short* __restrict__ cbh,
    const float* __restrict__ cnorm,
    float* __restrict__ bestv_ws, int* __restrict__ bestk_ws,
    float* __restrict__ zsq_ws) {
  __shared__ __align__(16) char smem[70656];
  char* ZT = smem;                                      // [64 cols][256 k] bf16, swizzled (prologue)
  float* cnorm_s = (float*)(smem + 65536);              // 1024 f32
  float* zred = (float*)(smem + 69632);                 // 256 f32

  const int t = threadIdx.x;
  const int l = t & 63, w = t >> 6, g = l >> 4, cl = l & 15;
  const int bid = blockIdx.x;
  // XCD pairing swizzle: bids {k, k+8} (same XCD under bid%8 round-robin)
  // are the two K-halves of the SAME coltile -> z tile shared in XCD L2.
  const int ct = (bid & 7) | ((bid >> 4) << 3);
  const int hf = (bid >> 3) & 1;
  const int b = ct >> 4, m0 = (ct & 15) * BN;
  const int rowbase = hf * 1024;
  const float* zb = z + (size_t)b * (D * HW) + m0;

  // ---- prologue: stage ZT = bf16(-2z) transposed+swizzled; zsq partials ----
  float zp = 0.f;
#pragma unroll 4
  for (int it = 0; it < 32; ++it) {
    int d0 = it * 8 + w * 2;
    float v0 = zb[(size_t)d0 * HW + l];
    float v1 = zb[(size_t)(d0 + 1) * HW + l];
    zp += v0 * v0 + v1 * v1;
    unsigned pk = (unsigned)f2bf(-2.f * v0) | ((unsigned)f2bf(-2.f * v1) << 16);
    *(unsigned*)(ZT + l * 512 + ((d0 * 2) ^ ((l & 7) << 4))) = pk;
  }
  zred[t] = zp;
#pragma unroll
  for (int i = 0; i < 4; ++i) cnorm_s[t + i * 256] = cnorm[rowbase + t + i * 256];
  __syncthreads();
  if (t < 64 && hf == 0)
    zsq_ws[ct * 64 + t] = (zred[t] + zred[t + 64]) + (zred[t + 128] + zred[t + 192]);

  // ---- load ALL B fragments to registers ----
  bf16x8 bvc[4][8];
#pragma unroll
  for (int s = 0; s < 8; ++s)
#pragma unroll
    for (int cf = 0; cf < 4; ++cf) {
      int c = cf * 16 + cl;
      bvc[cf][s] = *(const bf16x8*)(ZT + c * 512 + ((s * 64 + g * 16) ^ ((c & 7) << 4)));
    }
  __syncthreads();   // ZT reads done; bufs[0..3] = smem+0..65536 take over

  float bestvr[4]; int bestkr[4];
#pragma unroll
  for (int cf = 0; cf < 4; ++cf) { bestvr[cf] = 3.4e38f; bestkr[cf] = 0; }

  // prime pipeline: chunks 0,1 (buffer index == kt == chunk&3)
  stage_chunk(cbh, rowbase, 0, 0, smem, w, l);
  stage_chunk(cbh, rowbase, 0, 1, smem + 16384, w, l);

  for (int mt = 0; mt < 8; ++mt) {
    f32x4 acc[2][4];
#pragma unroll
    for (int mf = 0; mf < 2; ++mf)
#pragma unroll
      for (int cf = 0; cf < 4; ++cf) acc[mf][cf] = (f32x4){0.f, 0.f, 0.f, 0.f};

#pragma unroll
    for (int kt = 0; kt < 4; ++kt) {
      int p = mt * 4 + kt;
      if (p + 2 < 32) {
        int c2 = p + 2;
        stage_chunk(cbh, rowbase, c2 >> 2, c2 & 3, smem + (c2 & 3) * 16384, w, l);
        asm volatile("s_waitcnt vmcnt(8)" ::: "memory");   // chunk p complete
      } else if (p + 2 == 32) {
        asm volatile("s_waitcnt vmcnt(4)" ::: "memory");
      } else {
        asm volatile("s_waitcnt vmcnt(0)" ::: "memory");
      }
      __builtin_amdgcn_s_barrier();
      const char* Ac = smem + (p & 3) * 16384;
#pragma unroll
      for (int ks = 0; ks < 2; ++ks) {
        bf16x8 af[2];
#pragma unroll
        for (int mf = 0; mf < 2; ++mf) {
          int r = w * 32 + mf * 16 + cl;
          af[mf] = *(const bf16x8*)(Ac + r * 128 + ((ks * 64 + g * 16) ^ ((r & 7) << 4)));
        }
#pragma unroll
        for (int mf = 0; mf < 2; ++mf)
#pragma unroll
          for (int cf = 0; cf < 4; ++cf)
            acc[mf][cf] = __builtin_amdgcn_mfma_f32_16x16x32_bf16(
                af[mf], bvc[cf][kt * 2 + ks], acc[mf][cf], 0, 0, 0);
      }
    }

    // ---- argmin update: dist = ||c||^2 + (-2 z . c) ----
#pragma unroll
    for (int mf = 0; mf < 2; ++mf)
#pragma unroll
      for (int i = 0; i < 4; ++i) {
        int lr = mt * 128 + w * 32 + mf * 16 + g * 4 + i;   // C/D row map (m89)
        float cn = cnorm_s[lr];
        int grow = rowbase + lr;
#pragma unroll
        for (int cf = 0; cf < 4; ++cf) {
          float v = cn + acc[mf][cf][i];
          if (v < bestvr[cf]) { bestvr[cf] = v; bestkr[cf] = grow; }
        }
      }
  }

  // ---- reduce argmin across lanes/waves; write per-(ct,hf) results ----
  __syncthreads();
  float* redv = (float*)smem;            // [4 waves][4 cf][16]
  int* redk = (int*)(smem + 1024);
#pragma unroll
  for (int cf = 0; cf < 4; ++cf) {
    float v = bestvr[cf]; int kk = bestkr[cf];
#pragma unroll
    for (int off = 16; off < 64; off <<= 1) {
      float ov = __shfl_xor(v, off, 64);
      int ok = __shfl_xor(kk, off, 64);
      if (ov < v || (ov == v && ok < kk)) { v = ov; kk = ok; }
    }
    if (g == 0) { redv[(w * 4 + cf) * 16 + cl] = v; redk[(w * 4 + cf) * 16 + cl] = kk; }
  }
  __syncthreads();
  if (t < 64) {
    int cf = t >> 4, c2 = t & 15;
    float v = redv[cf * 16 + c2]; int kk = redk[cf * 16 + c2];
#pragma unroll
    for (int w2 = 1; w2 < 4; ++w2) {
      float ov = redv[(w2 * 4 + cf) * 16 + c2];
      int ok = redk[(w2 * 4 + cf) * 16 + c2];
      if (ov < v || (ov == v && ok < kk)) { v = ov; kk = ok; }
    }
    bestv_ws[(ct * 2 + hf) * 64 + t] = v;
    bestk_ws[(ct * 2 + hf) * 64 + t] = kk;
  }
}

// K3: merge halves, LDS-stage gathered rows, write q as float4-across-cols.
__global__ __launch_bounds__(256) void vq_epilogue(
    const float* __restrict__ cb, const float* __restrict__ bestv_ws,
    const int* __restrict__ bestk_ws, const float* __restrict__ zsq_ws,
    float* __restrict__ qout, float* __restrict__ partial) {
  __shared__ float cs[64][258];   // pad 258: 4-col read stride -> 2 lanes/bank (free)
  __shared__ int kbest_s[64];
  const int t = threadIdx.x, l = t & 63;
  const int ct = blockIdx.x;
  const int b = ct >> 4, m0 = (ct & 15) * BN;
  if (t < 64) {
    float v0 = bestv_ws[(ct * 2 + 0) * 64 + t]; int k0 = bestk_ws[(ct * 2 + 0) * 64 + t];
    float v1 = bestv_ws[(ct * 2 + 1) * 64 + t]; int k1 = bestk_ws[(ct * 2 + 1) * 64 + t];
    int kk = (v1 < v0) ? k1 : k0;
    float vv = (v1 < v0) ? v1 : v0;
    kbest_s[t] = kk;
    float cpart = zsq_ws[ct * 64 + t] + vv;    // sum_d (z-c)^2 for this column
#pragma unroll
    for (int off = 32; off; off >>= 1) cpart += __shfl_down(cpart, off, 64);
    if (t == 0) partial[ct] = cpart;
  }
  __syncthreads();
  // stage gathered codebook rows: 16 passes x 4 cols (one col per wave)
#pragma unroll 4
  for (int p = 0; p < 16; ++p) {
    int col = p * 4 + (t >> 6);
    int k = kbest_s[col];
    float4 cv = *(const float4*)(cb + (size_t)k * D + l * 4);
    *(float2*)&cs[col][l * 4] = make_float2(cv.x, cv.y);
    *(float2*)&cs[col][l * 4 + 2] = make_float2(cv.z, cv.w);
  }
  __syncthreads();
  // store: thread covers 4 consecutive cols x 16 d's -> float4 stores
  const int colg = t & 15, dbase = (t >> 4) * 16;
  float* qb = qout + (size_t)b * (D * HW) + m0 + colg * 4;
#pragma unroll 4
  for (int i = 0; i < 16; ++i) {
    int d = dbase + i;
    float4 o = make_float4(cs[colg * 4][d], cs[colg * 4 + 1][d],
                           cs[colg * 4 + 2][d], cs[colg * 4 + 3][d]);
    *(float4*)(qb + (size_t)d * HW) = o;
  }
}

// K4: deterministic reduction of 256 coltile partials -> loss scalars
__global__ __launch_bounds__(256) void vq_finalize(const float* __restrict__ partial,
                                                   float* __restrict__ out) {
  int t = threadIdx.x;
  float s = partial[t];
#pragma unroll
  for (int off = 32; off; off >>= 1) s += __shfl_down(s, off, 64);
  __shared__ float ws4[4];
  if ((t & 63) == 0) ws4[t >> 6] = s;
  __syncthreads();
  if (t == 0) {
    float tot = (ws4[0] + ws4[1]) + (ws4[2] + ws4[3]);
    float commit = tot / 4194304.0f;
    out[4194304] = 0.25f * commit;
    out[4194305] = commit;
  }
}

extern "C" void kernel_launch(void* const* d_in, const int* in_sizes, int n_in,
                              void* d_out, int out_size, void* d_ws, size_t ws_size,
                              hipStream_t stream) {
  const float* z = (const float*)d_in[0];
  const float* cb = (const float*)d_in[1];
  float* out = (float*)d_out;
  char* ws = (char*)d_ws;
  unsigned short* cbh = (unsigned short*)ws;                       // 1 MB
  float* cnorm   = (float*)(ws + 1048576);                         // 8 KB
  float* partial = (float*)(ws + 1056768);                         // 1 KB
  float* bestv_ws = (float*)(ws + 1057792);                        // 128 KB
  int*   bestk_ws = (int*)(ws + 1188864);                          // 128 KB
  float* zsq_ws   = (float*)(ws + 1319936);                        // 64 KB

  vq_prep<<<KCB, 256, 0, stream>>>(cb, cbh, cnorm);
  vq_main<<<512, 256, 0, stream>>>(z, cbh, cnorm, bestv_ws, bestk_ws, zsq_ws);
  vq_epilogue<<<256, 256, 0, stream>>>(cb, bestv_ws, bestk_ws, zsq_ws, out, partial);
  vq_finalize<<<1, 256, 0, stream>>>(partial, out);
}

// Round 5
// 33.302 us; speedup vs baseline: 1.6497x; 1.3113x over previous
//
#include <hip/hip_runtime.h>

#define D    256
#define KCB  2048
#define HW   1024
#define BN   64

typedef __attribute__((ext_vector_type(4))) int i32x4;

// K1: codebook fp32 -> i8 (scale 2048*127) + cnorm[row] = ||c||^2 (exact fp32)
__global__ __launch_bounds__(256) void vq_prep(const float* __restrict__ cb,
                                               unsigned* __restrict__ cbi8,
                                               float* __restrict__ cnorm) {
  int row = blockIdx.x;
  int t = threadIdx.x;
  float c = cb[(size_t)row * D + t];
  float s = c * c;
#pragma unroll
  for (int off = 32; off; off >>= 1) s += __shfl_down(s, off, 64);
  __shared__ float ws4[4];
  if ((t & 63) == 0) ws4[t >> 6] = s;
  __syncthreads();
  if (t == 0) cnorm[row] = (ws4[0] + ws4[1]) + (ws4[2] + ws4[3]);
  if (t < 64) {
    float4 cv = *(const float4*)(cb + (size_t)row * D + t * 4);
    int q0 = __float2int_rn(cv.x * 260096.0f);
    int q1 = __float2int_rn(cv.y * 260096.0f);
    int q2 = __float2int_rn(cv.z * 260096.0f);
    int q3 = __float2int_rn(cv.w * 260096.0f);
    cbi8[row * 64 + t] = (unsigned)(q0 & 255) | ((unsigned)(q1 & 255) << 8) |
                         ((unsigned)(q2 & 255) << 16) | ((unsigned)(q3 & 255) << 24);
  }
}

// stage one chunk (256 rows x 64 k i8 = 16KB): 2 glds per wave, linear LDS dest,
// k-slot pre-swizzled on the GLOBAL source (inverse of the read swizzle).
__device__ __forceinline__ void stage_chunk(const unsigned char* __restrict__ cbi8,
                                            int mt, int kt, char* dst, int w, int l) {
#pragma unroll
  for (int i = 0; i < 2; ++i) {
    int r = w * 32 + i * 16 + (l >> 2);
    int gsrc = (l & 3) ^ ((r >> 1) & 3);
    const unsigned char* gp =
        cbi8 + (((size_t)(mt * 256 + r)) << 8) + kt * 64 + gsrc * 16;
    __builtin_amdgcn_global_load_lds(
        (const __attribute__((address_space(1))) void*)gp,
        (__attribute__((address_space(3))) void*)(dst + w * 2048 + i * 1024 + l * 16),
        16, 0, 0);
  }
}

// K2: full-codebook i8 distance GEMM + argmin + q gather + commitment partial.
// grid = 256 (1 block/CU), 512 threads (8 waves). Triple-buffered staging,
// single barrier per phase, counted vmcnt(2).
__global__ __launch_bounds__(512, 2) void vq_main(
    const float* __restrict__ z, const unsigned char* __restrict__ cbi8,
    const float* __restrict__ cnorm, const float* __restrict__ cb,
    float* __restrict__ qout, float* __restrict__ partial) {
  __shared__ __align__(16) char smem[64256];
  // bufs: 3 x 16KB at 0/16384/32768. ZT overlaps bufs (prologue only).
  char* ZT = smem;                                   // [64 cols][256 k] i8, stride 272
  float* cnorm_s = (float*)(smem + 49152);           // 2048 f32
  float* zred   = (float*)(smem + 57344);            // 512 f32
  float* zsq_s  = (float*)(smem + 59392);            // 64 f32
  float* redv   = (float*)(smem + 59648);            // 512 f32
  int*   redk   = (int*)(smem + 61696);              // 512 i32
  int*   kbest_s = (int*)(smem + 63744);             // 64
  float* bestv_s = (float*)(smem + 64000);           // 64

  const int t = threadIdx.x;
  const int l = t & 63, w = t >> 6, g = l >> 4, cl = l & 15;
  const int ct = blockIdx.x;
  const int b = ct >> 4, m0 = (ct & 15) * BN;
  const float* zb = z + (size_t)b * (D * HW) + m0;
  const float SC = -2.0f * (6.0f / 127.0f) / 260096.0f;   // -2*sz*sc

  // ---- prologue: ZT = i8(z*127/6) transposed (col-major), stride-272 rows ----
  float zp = 0.f;
#pragma unroll
  for (int it = 0; it < 8; ++it) {
    int d0 = w * 32 + it * 4;
    float v0 = zb[(size_t)(d0 + 0) * HW + l];
    float v1 = zb[(size_t)(d0 + 1) * HW + l];
    float v2 = zb[(size_t)(d0 + 2) * HW + l];
    float v3 = zb[(size_t)(d0 + 3) * HW + l];
    zp += v0 * v0 + v1 * v1 + v2 * v2 + v3 * v3;
    int q0 = __float2int_rn(fminf(fmaxf(v0 * 21.1666667f, -127.f), 127.f));
    int q1 = __float2int_rn(fminf(fmaxf(v1 * 21.1666667f, -127.f), 127.f));
    int q2 = __float2int_rn(fminf(fmaxf(v2 * 21.1666667f, -127.f), 127.f));
    int q3 = __float2int_rn(fminf(fmaxf(v3 * 21.1666667f, -127.f), 127.f));
    unsigned pk = (unsigned)(q0 & 255) | ((unsigned)(q1 & 255) << 8) |
                  ((unsigned)(q2 & 255) << 16) | ((unsigned)(q3 & 255) << 24);
    *(unsigned*)(ZT + l * 272 + ((d0 >> 4) << 4) + (d0 & 15)) = pk;
  }
  zred[t] = zp;
#pragma unroll
  for (int i = 0; i < 4; ++i) cnorm_s[t + i * 512] = cnorm[t + i * 512];
  __syncthreads();
  if (t < 64) {
    float s = 0.f;
#pragma unroll
    for (int j = 0; j < 8; ++j) s += zred[j * 64 + t];
    zsq_s[t] = s;
  }

  // ---- all B fragments to registers: bvc[cf][ks] ----
  i32x4 bvc[4][4];
#pragma unroll
  for (int ks = 0; ks < 4; ++ks)
#pragma unroll
    for (int cf = 0; cf < 4; ++cf)
      bvc[cf][ks] = *(const i32x4*)(ZT + (cf * 16 + cl) * 272 + ((ks * 4 + g) << 4));
  asm volatile("s_waitcnt lgkmcnt(0)" ::: "memory");
  __syncthreads();   // ZT fully consumed; buffer region now owned by staging

  float bestvr[4]; int bestkr[4];
#pragma unroll
  for (int cf = 0; cf < 4; ++cf) { bestvr[cf] = 3.4e38f; bestkr[cf] = 0; }

  stage_chunk(cbi8, 0, 0, smem, w, l);   // chunk 0 -> buf 0

#pragma unroll
  for (int mt = 0; mt < 8; ++mt) {
    i32x4 acc[2][4];
#pragma unroll
    for (int mf = 0; mf < 2; ++mf)
#pragma unroll
      for (int cf = 0; cf < 4; ++cf) acc[mf][cf] = (i32x4){0, 0, 0, 0};

#pragma unroll
    for (int kt = 0; kt < 4; ++kt) {
      int c = mt * 4 + kt;
      if (c + 1 < 32) {
        int cn_ = c + 1;
        stage_chunk(cbi8, cn_ >> 2, cn_ & 3, smem + (cn_ % 3) * 16384, w, l);
        asm volatile("s_waitcnt vmcnt(2)" ::: "memory");   // chunk c complete
      } else {
        asm volatile("s_waitcnt vmcnt(0)" ::: "memory");
      }
      __builtin_amdgcn_s_barrier();
      const char* Ac = smem + (c % 3) * 16384;
      i32x4 af[2];
#pragma unroll
      for (int mf = 0; mf < 2; ++mf) {
        int r = w * 32 + mf * 16 + cl;
        af[mf] = *(const i32x4*)(Ac + r * 64 + ((g ^ ((r >> 1) & 3)) << 4));
      }
#pragma unroll
      for (int mf = 0; mf < 2; ++mf)
#pragma unroll
        for (int cf = 0; cf < 4; ++cf)
          acc[mf][cf] = __builtin_amdgcn_mfma_i32_16x16x64_i8(
              af[mf], bvc[cf][kt], acc[mf][cf], 0, 0, 0);
    }

    // ---- argmin: dist = ||c||^2 + SC*acc ----
#pragma unroll
    for (int mf = 0; mf < 2; ++mf)
#pragma unroll
      for (int i = 0; i < 4; ++i) {
        int lr = mt * 256 + w * 32 + mf * 16 + g * 4 + i;   // C/D row map (m89)
        float cn = cnorm_s[lr];
#pragma unroll
        for (int cf = 0; cf < 4; ++cf) {
          float v = fmaf(SC, (float)acc[mf][cf][i], cn);
          if (v < bestvr[cf]) { bestvr[cf] = v; bestkr[cf] = lr; }
        }
      }
  }

  // ---- global argmin across lanes/waves ----
  __syncthreads();
#pragma unroll
  for (int cf = 0; cf < 4; ++cf) {
    float v = bestvr[cf]; int kk = bestkr[cf];
#pragma unroll
    for (int off = 16; off < 64; off <<= 1) {
      float ov = __shfl_xor(v, off, 64);
      int ok = __shfl_xor(kk, off, 64);
      if (ov < v || (ov == v && ok < kk)) { v = ov; kk = ok; }
    }
    if (g == 0) { redv[(w * 4 + cf) * 16 + cl] = v; redk[(w * 4 + cf) * 16 + cl] = kk; }
  }
  __syncthreads();
  if (t < 64) {
    int cf = t >> 4, c2 = t & 15;
    float v = redv[cf * 16 + c2]; int kk = redk[cf * 16 + c2];
#pragma unroll
    for (int w2 = 1; w2 < 8; ++w2) {
      float ov = redv[(w2 * 4 + cf) * 16 + c2];
      int ok = redk[(w2 * 4 + cf) * 16 + c2];
      if (ov < v || (ov == v && ok < kk)) { v = ov; kk = ok; }
    }
    kbest_s[cf * 16 + c2] = kk;
    bestv_s[cf * 16 + c2] = v;
  }
  __syncthreads();

  // ---- commitment partial: sum_cols (||z||^2 + best(||c||^2 - 2 z.c)) ----
  if (t < 64) {
    float cpart = zsq_s[t] + bestv_s[t];
#pragma unroll
    for (int off = 32; off; off >>= 1) cpart += __shfl_down(cpart, off, 64);
    if (t == 0) partial[ct] = cpart;
  }

  // ---- q write: exact fp32 codebook gather, coalesced stores ----
  {
    int krow = kbest_s[l];
    const float* crow = cb + (size_t)krow * D + w * 32;
    float* qc = qout + (size_t)b * (D * HW) + (size_t)(w * 32) * HW + m0 + l;
#pragma unroll
    for (int i = 0; i < 8; ++i) {
      float4 cv = *(const float4*)(crow + i * 4);
      qc[(size_t)(i * 4 + 0) * HW] = cv.x;
      qc[(size_t)(i * 4 + 1) * HW] = cv.y;
      qc[(size_t)(i * 4 + 2) * HW] = cv.z;
      qc[(size_t)(i * 4 + 3) * HW] = cv.w;
    }
  }
}

// K3: deterministic reduction of 256 partials -> loss scalars
__global__ __launch_bounds__(256) void vq_finalize(const float* __restrict__ partial,
                                                   float* __restrict__ out) {
  int t = threadIdx.x;
  float s = partial[t];
#pragma unroll
  for (int off = 32; off; off >>= 1) s += __shfl_down(s, off, 64);
  __shared__ float ws4[4];
  if ((t & 63) == 0) ws4[t >> 6] = s;
  __syncthreads();
  if (t == 0) {
    float tot = (ws4[0] + ws4[1]) + (ws4[2] + ws4[3]);
    float commit = tot / 4194304.0f;
    out[4194304] = 0.25f * commit;
    out[4194305] = commit;
  }
}

extern "C" void kernel_launch(void* const* d_in, const int* in_sizes, int n_in,
                              void* d_out, int out_size, void* d_ws, size_t ws_size,
                              hipStream_t stream) {
  const float* z = (const float*)d_in[0];
  const float* cb = (const float*)d_in[1];
  float* out = (float*)d_out;
  char* ws = (char*)d_ws;
  unsigned* cbi8 = (unsigned*)ws;                    // 512 KB
  float* cnorm   = (float*)(ws + 524288);            // 8 KB
  float* partial = (float*)(ws + 532480);            // 1 KB

  vq_prep<<<KCB, 256, 0, stream>>>(cb, cbi8, cnorm);
  vq_main<<<256, 512, 0, stream>>>(z, (const unsigned char*)cbi8, cnorm, cb, out, partial);
  vq_finalize<<<1, 256, 0, stream>>>(partial, out);
}